// Round 5
// baseline (902.302 us; speedup 1.0000x reference)
//
#include <hip/hip_runtime.h>

// PolynomialSketch: out[b,o] = (1/64)*exp(0.5*lv) * prod_k( sum_i x[b,i]*exp(-lls)*W[k,i,o] )
// B=16384, D_IN=1024, D_FEAT=4096, DEGREE=3

#define BATCH 16384
#define DIN   1024
#define DFEAT 4096

typedef short short8 __attribute__((ext_vector_type(8)));
typedef float f32x4  __attribute__((ext_vector_type(4)));
typedef unsigned short ushort8v __attribute__((ext_vector_type(8)));

__device__ __forceinline__ unsigned short f2bf(float f) {
  unsigned int u = __float_as_uint(f);
  u += 0x7FFFu + ((u >> 16) & 1u);   // round-to-nearest-even
  return (unsigned short)(u >> 16);
}

// ---- prelude 1: xs_bf16[b,i] = bf16(x[b,i] * exp(-log_ls)) ----
__global__ void cast_x_kernel(const float4* __restrict__ x,
                              const float* __restrict__ log_ls,
                              ushort8v* __restrict__ xs) {
  float inv = expf(-log_ls[0]);
  int i = blockIdx.x * 256 + threadIdx.x;
  float4 v0 = x[i * 2];
  float4 v1 = x[i * 2 + 1];
  ushort8v o;
  o[0] = f2bf(v0.x * inv); o[1] = f2bf(v0.y * inv);
  o[2] = f2bf(v0.z * inv); o[3] = f2bf(v0.w * inv);
  o[4] = f2bf(v1.x * inv); o[5] = f2bf(v1.y * inv);
  o[6] = f2bf(v1.z * inv); o[7] = f2bf(v1.w * inv);
  xs[i] = o;
}

// ---- prelude 2: Wt[d, o, i] = bf16(W[d, i, o]) ----
__global__ void transpose_w_kernel(const float* __restrict__ W,
                                   unsigned short* __restrict__ Wt) {
  __shared__ float tile[32][65];
  int d  = blockIdx.z;
  int i0 = blockIdx.y * 32;   // d_in
  int o0 = blockIdx.x * 64;   // d_feat
  int tid = threadIdx.x;      // 0..255
  const float* src = W + (size_t)d * DIN * DFEAT + (size_t)i0 * DFEAT + o0;
  #pragma unroll
  for (int j = 0; j < 2; ++j) {
    int idx = j * 256 + tid;       // 0..511
    int r = idx >> 4;              // i row 0..31
    int c = (idx & 15) * 4;        // o col
    float4 v = *(const float4*)(src + (size_t)r * DFEAT + c);
    tile[r][c + 0] = v.x; tile[r][c + 1] = v.y;
    tile[r][c + 2] = v.z; tile[r][c + 3] = v.w;
  }
  __syncthreads();
  unsigned short* dst = Wt + (size_t)d * DFEAT * DIN + (size_t)o0 * DIN + i0;
  #pragma unroll
  for (int j = 0; j < 2; ++j) {
    int idx = j * 256 + tid;
    int r = idx >> 3;              // o row 0..63
    int c = (idx & 7) * 4;         // i col
    ushort4 u;
    u.x = f2bf(tile[c + 0][r]);
    u.y = f2bf(tile[c + 1][r]);
    u.z = f2bf(tile[c + 2][r]);
    u.w = f2bf(tile[c + 3][r]);
    *(ushort4*)(dst + (size_t)r * DIN + c) = u;
  }
}

// ---- main fused kernel ----
// BM=128, BN=64, BK=64. 256 threads = 4 waves in 2x2; wave tile 64x32 per degree.
//
// ROUND-5 STRUCTURE: A DIRECT-TO-REGISTER (no A in LDS). Round-4 counters:
// MfmaUtil 41.8% with LDS traffic (240 KB/CU/tile-pair ~= 1875-2800 cy) tied
// with MFMA pipe time (1862 cy) — co-equal pipes serializing. A-fragments are
// contiguous 16B row slices of xs, loaded per-lane as global_load_dwordx4
// (lane l: row base+(l&15), k-off (l>>4)*8), double-buffered in registers,
// issued ONE FULL TILE ahead. LDS now holds only B (3 mats, 4x reuse):
// 48 KiB, traffic 144 KB/CU/tile-pair ~= 1125-1700 cy < MFMA 1862 cy.
//
// Read-ahead rotation per tile t (CB=t&1, NB=CB^1):
//   P0: MFMA mat0 (a(t), b0(t)); ds_read b1(t)<-CB; stage B0(t+1); load A(t+1)
//   P1: MFMA mat1 (a(t), b1(t)); ds_read b2(t)<-CB; stage B1(t+1)
//   P2: MFMA mat2 (a(t), b2(t)); ds_read b0(t+1)<-NB; stage B2(t+1)
// vmcnt ledger (per-wave issue/tile: P0: B0' 2 then A' 8; P1: B1' 2; P2: B2' 2):
//   P0 entry: outstanding [a(t)8, b1(t)2, b2(t)2]=12, need a+b1 -> vmcnt(2)
//   P1 entry: outstanding [b2(t)2, b0'2, a'8]=12,     need b2   -> vmcnt(10)
//   P2 entry: outstanding [b0'2, a'8, b1'2]=12,       need b0'  -> vmcnt(10)
//   prologue: [b0 2, a 8, b1 2, b2 2]=14, drain b0 -> vmcnt(12); tail 2/0.
// Phase entry is STRICT: waitcnt (own loads) -> s_barrier (all waves) ->
// sched_barrier(0) (rule #18). Issue order B0' BEFORE A' is pinned by a
// sched_barrier(0) between them (ledger depends on it).
// B LDS: rows of 8 16B-chunks, chunk-XOR-swizzled phys p = c ^ (row&7),
// swizzle applied on the GLOBAL source address (linear gload_lds dest).
__global__ __launch_bounds__(256, 2) void sketch_gemm_kernel(
    const unsigned short* __restrict__ xs,   // [16384][1024] bf16 bits
    const unsigned short* __restrict__ Wt,   // [3][4096][1024] bf16 bits
    const float* __restrict__ log_var,
    float* __restrict__ out) {               // [16384][4096] fp32
  __shared__ unsigned short Bs[2][3][64 * 64];     // 48 KB (B only)

  const int tid  = threadIdx.x;
  const int lane = tid & 63;
  const int w    = tid >> 6;      // 0..3
  const int wm   = w >> 1;        // wave row (0..1)
  const int wn   = w & 1;         // wave col (0..1)
  const int row  = lane & 15;
  const int quad = lane >> 4;

  // XCD-aware mapping: bid % 8 -> XCD; 8 bn blocks per XCD slice (3 MB of B
  // fits 4 MB per-XCD L2); 8 consecutive blocks share one bm. 8192 % 8 == 0.
  int bid = blockIdx.x;
  int xcd = bid & 7;
  int t0  = bid >> 3;                // 0..1023 per XCD
  int bn  = (xcd << 3) + (t0 & 7);   // 0..63
  int bm  = t0 >> 3;                 // 0..127

  f32x4 acc[3][4][2];
  #pragma unroll
  for (int d = 0; d < 3; ++d)
    #pragma unroll
    for (int mi = 0; mi < 4; ++mi)
      #pragma unroll
      for (int ni = 0; ni < 2; ++ni)
        acc[d][mi][ni] = (f32x4){0.f, 0.f, 0.f, 0.f};

  const unsigned short* xsrc = xs + (size_t)(bm * 128) * DIN;
  const unsigned short* wsrc = Wt + (size_t)(bn * 64) * DIN;
  // Per-lane A base: row = wm*64 + (lane&15), k-offset = (lane>>4)*8.
  // Fragment load: a[mi][kh] <- aptr + mi*16*DIN + kh*32 + k0  (16B aligned).
  const unsigned short* aptr = xsrc + (size_t)(wm * 64 + row) * DIN + (quad << 3);

#define STAGE_B(DSTBUF, MAT, K0)                                               \
  {                                                                            \
    _Pragma("unroll")                                                          \
    for (int j = 0; j < 2; ++j) {                                              \
      int gi = (w << 1) + j;                                                   \
      int gc = (gi << 6) + lane;          /* chunk id 0..511 */                \
      int nn = gc >> 3;                                                        \
      int cc = (gc & 7) ^ (nn & 7);                                            \
      __builtin_amdgcn_global_load_lds(                                        \
          (const __attribute__((address_space(1))) void*)(                     \
              wsrc + (size_t)(MAT) * (DFEAT * DIN) + (size_t)nn * DIN + (K0) + cc * 8), \
          (__attribute__((address_space(3))) void*)(&Bs[DSTBUF][MAT][gi << 9]),\
          16, 0, 0);                                                           \
    }                                                                          \
  }

#define LOAD_A(DST, K0)                                                        \
  _Pragma("unroll")                                                            \
  for (int mi = 0; mi < 4; ++mi) {                                             \
    _Pragma("unroll")                                                          \
    for (int kh = 0; kh < 2; ++kh) {                                           \
      DST[mi][kh] = *(const short8*)(aptr + (size_t)(mi * 16) * DIN +          \
                                     (K0) + kh * 32);                          \
    }                                                                          \
  }

#define READ_B(SRCBUF, MAT, DST)                                               \
  _Pragma("unroll")                                                            \
  for (int ni = 0; ni < 2; ++ni) {                                             \
    _Pragma("unroll")                                                          \
    for (int kh = 0; kh < 2; ++kh) {                                           \
      int nn = wn * 32 + ni * 16 + row;                                        \
      int pp = ((kh << 2) + quad) ^ (nn & 7);                                  \
      DST[ni][kh] = *(const short8*)(&Bs[SRCBUF][MAT][nn * 64 + pp * 8]);      \
    }                                                                          \
  }

// MFMA on fragments produced at least one phase earlier (lgkm/vm waits ~free).
#define MFMA_P(MAT, AARR, BARR)                                                \
  __builtin_amdgcn_s_setprio(1);                                               \
  _Pragma("unroll")                                                            \
  for (int mi = 0; mi < 4; ++mi)                                               \
    _Pragma("unroll")                                                          \
    for (int ni = 0; ni < 2; ++ni)                                             \
      _Pragma("unroll")                                                        \
      for (int kh = 0; kh < 2; ++kh)                                           \
        acc[MAT][mi][ni] = __builtin_amdgcn_mfma_f32_16x16x32_bf16(            \
            AARR[mi][kh], BARR[ni][kh], acc[MAT][mi][ni], 0, 0, 0);            \
  __builtin_amdgcn_s_setprio(0);                                               \
  __builtin_amdgcn_sched_barrier(0);

#define ENTRY(N)                                                               \
  asm volatile("s_waitcnt vmcnt(" #N ")" ::: "memory");                        \
  __builtin_amdgcn_s_barrier();                                                \
  __builtin_amdgcn_sched_barrier(0);

// One K-tile, 3 phases. AC/AA = a-frag cur/next (dbuf); BX/BY = b-frag
// ping-pong; CB/NB = LDS buffer indices (compile-time 0/1).
#define TILE_BODY(T, AC, AA, BX, BY, CB, NB)                                   \
  {                                                                            \
    const int kn_ = ((T) + 1) << 6;                                            \
    /* P0: mat0; read b1(t); stage B0(t+1); load A(t+1) */                     \
    ENTRY(2);                                                                  \
    READ_B(CB, 1, BY);                                                         \
    STAGE_B(NB, 0, kn_);                                                       \
    __builtin_amdgcn_sched_barrier(0);  /* pin: B0' issued before A' */        \
    LOAD_A(AA, kn_);                                                           \
    __builtin_amdgcn_sched_barrier(0);                                         \
    MFMA_P(0, AC, BX);                                                         \
    /* P1: mat1; read b2(t); stage B1(t+1) */                                  \
    ENTRY(10);                                                                 \
    READ_B(CB, 2, BX);                                                         \
    STAGE_B(NB, 1, kn_);                                                       \
    __builtin_amdgcn_sched_barrier(0);                                         \
    MFMA_P(1, AC, BY);                                                         \
    /* P2: mat2; read b0(t+1) from NB; stage B2(t+1) */                        \
    ENTRY(10);                                                                 \
    READ_B(NB, 0, BY);                                                         \
    STAGE_B(NB, 2, kn_);                                                       \
    __builtin_amdgcn_sched_barrier(0);                                         \
    MFMA_P(2, AC, BX);                                                         \
  }

  short8 a0[4][2], a1[4][2];   // A fragments (direct-from-global), tile dbuf
  short8 bx[2][2], by[2][2];   // B fragments, role-swap per tile

  // prologue: issue b0(0), a(0), b1(0), b2(0) -> queue [b0 2, a 8, b1 2, b2 2]
  STAGE_B(0, 0, 0);
  __builtin_amdgcn_sched_barrier(0);
  LOAD_A(a0, 0);
  __builtin_amdgcn_sched_barrier(0);
  STAGE_B(0, 1, 0);
  STAGE_B(0, 2, 0);
  asm volatile("s_waitcnt vmcnt(12)" ::: "memory");   // b0(0) landed
  __builtin_amdgcn_s_barrier();
  __builtin_amdgcn_sched_barrier(0);
  READ_B(0, 0, bx);                                   // b0(0) fragments

  #pragma unroll 1
  for (int i = 0; i < 7; ++i) {
    const int t = i * 2;
    TILE_BODY(t,     a0, a1, bx, by, 0, 1);
    TILE_BODY(t + 1, a1, a0, by, bx, 1, 0);
  }
  TILE_BODY(14, a0, a1, bx, by, 0, 1);

  // ---- tail: tile 15 (buf 1; AC=a1; b0(15) in by; no prefetch) ----
  ENTRY(2);                       // drain a(15)+B1(15)
  READ_B(1, 1, bx);
  __builtin_amdgcn_sched_barrier(0);
  MFMA_P(0, a1, by);

  ENTRY(0);                       // drain B2(15)
  READ_B(1, 2, by);
  __builtin_amdgcn_sched_barrier(0);
  MFMA_P(1, a1, bx);

  MFMA_P(2, a1, by);

  // epilogue: out = acc0*acc1*acc2 * (1/64)*exp(0.5*lv)
  float sc = 0.015625f * expf(0.5f * log_var[0]);
  #pragma unroll
  for (int mi = 0; mi < 4; ++mi) {
    #pragma unroll
    for (int ni = 0; ni < 2; ++ni) {
      int colg = bn * 64 + wn * 32 + ni * 16 + row;
      int rowg = bm * 128 + wm * 64 + mi * 16 + quad * 4;
      #pragma unroll
      for (int t2 = 0; t2 < 4; ++t2) {
        float v = acc[0][mi][ni][t2] * acc[1][mi][ni][t2] * acc[2][mi][ni][t2] * sc;
        out[(size_t)(rowg + t2) * DFEAT + colg] = v;
      }
    }
  }
#undef STAGE_B
#undef LOAD_A
#undef READ_B
#undef MFMA_P
#undef ENTRY
#undef TILE_BODY
}

extern "C" void kernel_launch(void* const* d_in, const int* in_sizes, int n_in,
                              void* d_out, int out_size, void* d_ws, size_t ws_size,
                              hipStream_t stream) {
  const float* x   = (const float*)d_in[0];
  const float* W   = (const float*)d_in[1];
  const float* lls = (const float*)d_in[2];
  const float* lv  = (const float*)d_in[3];
  float* out = (float*)d_out;

  unsigned short* xs = (unsigned short*)d_ws;                       // 32 MiB
  unsigned short* Wt = xs + (size_t)BATCH * DIN;                    // 24 MiB

  cast_x_kernel<<<BATCH * DIN / 8 / 256, 256, 0, stream>>>(
      (const float4*)x, lls, (ushort8v*)xs);

  transpose_w_kernel<<<dim3(DFEAT / 64, DIN / 32, 3), dim3(256), 0, stream>>>(W, Wt);

  sketch_gemm_kernel<<<(BATCH / 128) * (DFEAT / 64), 256, 0, stream>>>(xs, Wt, lv, out);
}

// Round 7
// 688.522 us; speedup vs baseline: 1.3105x; 1.3105x over previous
//
#include <hip/hip_runtime.h>

// PolynomialSketch: out[b,o] = (1/64)*exp(0.5*lv) * prod_k( sum_i x[b,i]*exp(-lls)*W[k,i,o] )
// B=16384, D_IN=1024, D_FEAT=4096, DEGREE=3

#define BATCH 16384
#define DIN   1024
#define DFEAT 4096

typedef short short8 __attribute__((ext_vector_type(8)));
typedef float f32x4  __attribute__((ext_vector_type(4)));
typedef unsigned short ushort8v __attribute__((ext_vector_type(8)));

__device__ __forceinline__ unsigned short f2bf(float f) {
  unsigned int u = __float_as_uint(f);
  u += 0x7FFFu + ((u >> 16) & 1u);   // round-to-nearest-even
  return (unsigned short)(u >> 16);
}

// ---- prelude 1: xs fragment-major = bf16(x * exp(-log_ls)) ----
// xs is stored in MFMA-FRAGMENT-MAJOR order so the GEMM's A loads are
// contiguous coalesced streams (round-5's row-major per-lane A loads were
// 16-way scattered gathers -> TA/TCP serialization, MfmaUtil 42->26.5%).
// Layout: chunk[(rb*32 + kc)*64 + l] (16B each), where for fragment
// (rb = row/16, kc = k/32): lane l holds row rb*16+(l&15), k = kc*32+(l>>4)*8.
__global__ void cast_x_kernel(const float4* __restrict__ x,
                              const float* __restrict__ log_ls,
                              ushort8v* __restrict__ xs) {
  float inv = expf(-log_ls[0]);
  int i  = blockIdx.x * 256 + threadIdx.x;   // i = r*128 + k8  (k8 = k/8)
  int r  = i >> 7;
  int k8 = i & 127;
  float4 v0 = x[i * 2];
  float4 v1 = x[i * 2 + 1];
  ushort8v o;
  o[0] = f2bf(v0.x * inv); o[1] = f2bf(v0.y * inv);
  o[2] = f2bf(v0.z * inv); o[3] = f2bf(v0.w * inv);
  o[4] = f2bf(v1.x * inv); o[5] = f2bf(v1.y * inv);
  o[6] = f2bf(v1.z * inv); o[7] = f2bf(v1.w * inv);
  int rb = r >> 4;                 // row-block (16 rows)
  int kc = k8 >> 2;                // k-chunk (32 k)
  int q  = k8 & 3;                 // quad within k-chunk
  int l  = q * 16 + (r & 15);      // lane in fragment
  xs[((rb * 32 + kc) << 6) + l] = o;
}

// ---- prelude 2: Wt[d, o, i] = bf16(W[d, i, o]) ----
__global__ void transpose_w_kernel(const float* __restrict__ W,
                                   unsigned short* __restrict__ Wt) {
  __shared__ float tile[32][65];
  int d  = blockIdx.z;
  int i0 = blockIdx.y * 32;   // d_in
  int o0 = blockIdx.x * 64;   // d_feat
  int tid = threadIdx.x;      // 0..255
  const float* src = W + (size_t)d * DIN * DFEAT + (size_t)i0 * DFEAT + o0;
  #pragma unroll
  for (int j = 0; j < 2; ++j) {
    int idx = j * 256 + tid;       // 0..511
    int r = idx >> 4;              // i row 0..31
    int c = (idx & 15) * 4;        // o col
    float4 v = *(const float4*)(src + (size_t)r * DFEAT + c);
    tile[r][c + 0] = v.x; tile[r][c + 1] = v.y;
    tile[r][c + 2] = v.z; tile[r][c + 3] = v.w;
  }
  __syncthreads();
  unsigned short* dst = Wt + (size_t)d * DFEAT * DIN + (size_t)o0 * DIN + i0;
  #pragma unroll
  for (int j = 0; j < 2; ++j) {
    int idx = j * 256 + tid;
    int r = idx >> 3;              // o row 0..63
    int c = (idx & 7) * 4;         // i col
    ushort4 u;
    u.x = f2bf(tile[c + 0][r]);
    u.y = f2bf(tile[c + 1][r]);
    u.z = f2bf(tile[c + 2][r]);
    u.w = f2bf(tile[c + 3][r]);
    *(ushort4*)(dst + (size_t)r * DIN + c) = u;
  }
}

// ---- main fused kernel ----
// BM=128, BN=64, BK=64. 256 threads = 4 waves in 2x2; wave tile 64x32 per degree.
//
// A DIRECT-TO-REGISTER from FRAGMENT-MAJOR xs (see cast_x). Same structure/
// ledger as round-5 (correctness-verified); only the A-load addressing changed
// from 16-way row gather to contiguous 1KB streams. LDS holds only B (3 mats,
// double-buffered): 48 KiB. LDS-port traffic per CU-slot drops from ~2880cy
// (R4: 160 instr reads + 80 writes @12cy) to ~1730cy < MFMA 1862cy.
//
// Read-ahead rotation per tile t (CB=t&1, NB=CB^1):
//   P0: MFMA mat0 (a(t), b0(t)); ds_read b1(t)<-CB; stage B0(t+1); load A(t+1)
//   P1: MFMA mat1 (a(t), b1(t)); ds_read b2(t)<-CB; stage B1(t+1)
//   P2: MFMA mat2 (a(t), b2(t)); ds_read b0(t+1)<-NB; stage B2(t+1)
// vmcnt ledger (per-wave issue/tile: P0: B0' 2 then A' 8; P1: B1' 2; P2: B2' 2):
//   P0 entry: outstanding [a(t)8, B1(t)2, B2(t)2]=12, need a+B1 -> vmcnt(2)
//   P1 entry: outstanding [B2(t)2, B0'2, a'8]=12,     need B2   -> vmcnt(10)
//   P2 entry: outstanding [B0'2, a'8, B1'2]=12,       need B0'  -> vmcnt(10)
//   prologue: [B0 2, a 8, B1 2, B2 2]=14, drain B0 -> vmcnt(12); tail 2/0.
// Phase entry is STRICT: waitcnt (own loads) -> s_barrier (all waves) ->
// sched_barrier(0) (rule #18). Issue order B0' BEFORE A' pinned by a
// sched_barrier(0) between them (ledger depends on it).
// B LDS: rows of 8 16B-chunks, chunk-XOR-swizzled phys p = c ^ (row&7),
// swizzle applied on the GLOBAL source address (linear gload_lds dest).
__global__ __launch_bounds__(256, 2) void sketch_gemm_kernel(
    const unsigned short* __restrict__ xs,   // fragment-major bf16 bits
    const unsigned short* __restrict__ Wt,   // [3][4096][1024] bf16 bits
    const float* __restrict__ log_var,
    float* __restrict__ out) {               // [16384][4096] fp32
  __shared__ unsigned short Bs[2][3][64 * 64];     // 48 KB (B only)

  const int tid  = threadIdx.x;
  const int lane = tid & 63;
  const int w    = tid >> 6;      // 0..3
  const int wm   = w >> 1;        // wave row (0..1)
  const int wn   = w & 1;         // wave col (0..1)
  const int row  = lane & 15;
  const int quad = lane >> 4;

  // XCD-aware mapping: bid % 8 -> XCD; 8 bn blocks per XCD slice (3 MB of B
  // fits 4 MB per-XCD L2); 8 consecutive blocks share one bm. 8192 % 8 == 0.
  int bid = blockIdx.x;
  int xcd = bid & 7;
  int t0  = bid >> 3;                // 0..1023 per XCD
  int bn  = (xcd << 3) + (t0 & 7);   // 0..63
  int bm  = t0 >> 3;                 // 0..127

  f32x4 acc[3][4][2];
  #pragma unroll
  for (int d = 0; d < 3; ++d)
    #pragma unroll
    for (int mi = 0; mi < 4; ++mi)
      #pragma unroll
      for (int ni = 0; ni < 2; ++ni)
        acc[d][mi][ni] = (f32x4){0.f, 0.f, 0.f, 0.f};

  const unsigned short* wsrc = Wt + (size_t)(bn * 64) * DIN;
  // A fragment-major: chunk(mi, t, kh) = ((rbw+mi)*32 + t*2 + kh)*64 + lane,
  // each chunk 8 ushorts. rbw = this wave's row-block base.
  const int rbw = bm * 8 + wm * 4;
  const unsigned short* aF = xs;

#define STAGE_B(DSTBUF, MAT, K0)                                               \
  {                                                                            \
    _Pragma("unroll")                                                          \
    for (int j = 0; j < 2; ++j) {                                              \
      int gi = (w << 1) + j;                                                   \
      int gc = (gi << 6) + lane;          /* chunk id 0..511 */                \
      int nn = gc >> 3;                                                        \
      int cc = (gc & 7) ^ (nn & 7);                                            \
      __builtin_amdgcn_global_load_lds(                                        \
          (const __attribute__((address_space(1))) void*)(                     \
              wsrc + (size_t)(MAT) * (DFEAT * DIN) + (size_t)nn * DIN + (K0) + cc * 8), \
          (__attribute__((address_space(3))) void*)(&Bs[DSTBUF][MAT][gi << 9]),\
          16, 0, 0);                                                           \
    }                                                                          \
  }

#define LOAD_A(DST, T)                                                         \
  _Pragma("unroll")                                                            \
  for (int mi = 0; mi < 4; ++mi) {                                             \
    _Pragma("unroll")                                                          \
    for (int kh = 0; kh < 2; ++kh) {                                           \
      DST[mi][kh] = *(const short8*)(aF +                                      \
          ((size_t)((((rbw + mi) << 5) + (T) * 2 + kh) << 9) + (lane << 3)));  \
    }                                                                          \
  }

#define READ_B(SRCBUF, MAT, DST)                                               \
  _Pragma("unroll")                                                            \
  for (int ni = 0; ni < 2; ++ni) {                                             \
    _Pragma("unroll")                                                          \
    for (int kh = 0; kh < 2; ++kh) {                                           \
      int nn = wn * 32 + ni * 16 + row;                                        \
      int pp = ((kh << 2) + quad) ^ (nn & 7);                                  \
      DST[ni][kh] = *(const short8*)(&Bs[SRCBUF][MAT][nn * 64 + pp * 8]);      \
    }                                                                          \
  }

// MFMA on fragments produced at least one phase earlier (lgkm/vm waits ~free).
#define MFMA_P(MAT, AARR, BARR)                                                \
  __builtin_amdgcn_s_setprio(1);                                               \
  _Pragma("unroll")                                                            \
  for (int mi = 0; mi < 4; ++mi)                                               \
    _Pragma("unroll")                                                          \
    for (int ni = 0; ni < 2; ++ni)                                             \
      _Pragma("unroll")                                                        \
      for (int kh = 0; kh < 2; ++kh)                                           \
        acc[MAT][mi][ni] = __builtin_amdgcn_mfma_f32_16x16x32_bf16(            \
            AARR[mi][kh], BARR[ni][kh], acc[MAT][mi][ni], 0, 0, 0);            \
  __builtin_amdgcn_s_setprio(0);                                               \
  __builtin_amdgcn_sched_barrier(0);

#define ENTRY(N)                                                               \
  asm volatile("s_waitcnt vmcnt(" #N ")" ::: "memory");                        \
  __builtin_amdgcn_s_barrier();                                                \
  __builtin_amdgcn_sched_barrier(0);

// One K-tile, 3 phases. AC/AA = a-frag cur/next (dbuf); BX/BY = b-frag
// ping-pong; CB/NB = LDS buffer indices (compile-time 0/1).
#define TILE_BODY(T, AC, AA, BX, BY, CB, NB)                                   \
  {                                                                            \
    const int kn_ = ((T) + 1) << 6;                                            \
    /* P0: mat0; read b1(t); stage B0(t+1); load A(t+1) */                     \
    ENTRY(2);                                                                  \
    READ_B(CB, 1, BY);                                                         \
    STAGE_B(NB, 0, kn_);                                                       \
    __builtin_amdgcn_sched_barrier(0);  /* pin: B0' issued before A' */        \
    LOAD_A(AA, (T) + 1);                                                       \
    __builtin_amdgcn_sched_barrier(0);                                         \
    MFMA_P(0, AC, BX);                                                         \
    /* P1: mat1; read b2(t); stage B1(t+1) */                                  \
    ENTRY(10);                                                                 \
    READ_B(CB, 2, BX);                                                         \
    STAGE_B(NB, 1, kn_);                                                       \
    __builtin_amdgcn_sched_barrier(0);                                         \
    MFMA_P(1, AC, BY);                                                         \
    /* P2: mat2; read b0(t+1) from NB; stage B2(t+1) */                        \
    ENTRY(10);                                                                 \
    READ_B(NB, 0, BY);                                                         \
    STAGE_B(NB, 2, kn_);                                                       \
    __builtin_amdgcn_sched_barrier(0);                                         \
    MFMA_P(2, AC, BX);                                                         \
  }

  short8 a0[4][2], a1[4][2];   // A fragments (direct-from-global), tile dbuf
  short8 bx[2][2], by[2][2];   // B fragments, role-swap per tile

  // prologue: issue b0(0), a(0), b1(0), b2(0) -> queue [B0 2, a 8, B1 2, B2 2]
  STAGE_B(0, 0, 0);
  __builtin_amdgcn_sched_barrier(0);
  LOAD_A(a0, 0);
  __builtin_amdgcn_sched_barrier(0);
  STAGE_B(0, 1, 0);
  STAGE_B(0, 2, 0);
  asm volatile("s_waitcnt vmcnt(12)" ::: "memory");   // B0(0) landed
  __builtin_amdgcn_s_barrier();
  __builtin_amdgcn_sched_barrier(0);
  READ_B(0, 0, bx);                                   // b0(0) fragments

  #pragma unroll 1
  for (int i = 0; i < 7; ++i) {
    const int t = i * 2;
    TILE_BODY(t,     a0, a1, bx, by, 0, 1);
    TILE_BODY(t + 1, a1, a0, by, bx, 1, 0);
  }
  TILE_BODY(14, a0, a1, bx, by, 0, 1);

  // ---- tail: tile 15 (buf 1; AC=a1; b0(15) in by; no prefetch) ----
  ENTRY(2);                       // drain a(15)+B1(15)
  READ_B(1, 1, bx);
  __builtin_amdgcn_sched_barrier(0);
  MFMA_P(0, a1, by);

  ENTRY(0);                       // drain B2(15)
  READ_B(1, 2, by);
  __builtin_amdgcn_sched_barrier(0);
  MFMA_P(1, a1, bx);

  MFMA_P(2, a1, by);

  // epilogue: out = acc0*acc1*acc2 * (1/64)*exp(0.5*lv)
  float sc = 0.015625f * expf(0.5f * log_var[0]);
  #pragma unroll
  for (int mi = 0; mi < 4; ++mi) {
    #pragma unroll
    for (int ni = 0; ni < 2; ++ni) {
      int colg = bn * 64 + wn * 32 + ni * 16 + row;
      int rowg = bm * 128 + wm * 64 + mi * 16 + quad * 4;
      #pragma unroll
      for (int t2 = 0; t2 < 4; ++t2) {
        float v = acc[0][mi][ni][t2] * acc[1][mi][ni][t2] * acc[2][mi][ni][t2] * sc;
        out[(size_t)(rowg + t2) * DFEAT + colg] = v;
      }
    }
  }
#undef STAGE_B
#undef LOAD_A
#undef READ_B
#undef MFMA_P
#undef ENTRY
#undef TILE_BODY
}

extern "C" void kernel_launch(void* const* d_in, const int* in_sizes, int n_in,
                              void* d_out, int out_size, void* d_ws, size_t ws_size,
                              hipStream_t stream) {
  const float* x   = (const float*)d_in[0];
  const float* W   = (const float*)d_in[1];
  const float* lls = (const float*)d_in[2];
  const float* lv  = (const float*)d_in[3];
  float* out = (float*)d_out;

  unsigned short* xs = (unsigned short*)d_ws;                       // 32 MiB
  unsigned short* Wt = xs + (size_t)BATCH * DIN;                    // 24 MiB

  cast_x_kernel<<<BATCH * DIN / 8 / 256, 256, 0, stream>>>(
      (const float4*)x, lls, (ushort8v*)xs);

  transpose_w_kernel<<<dim3(DFEAT / 64, DIN / 32, 3), dim3(256), 0, stream>>>(W, Wt);

  sketch_gemm_kernel<<<(BATCH / 128) * (DFEAT / 64), 256, 0, stream>>>(xs, Wt, lv, out);
}

// Round 8
// 669.055 us; speedup vs baseline: 1.3486x; 1.0291x over previous
//
#include <hip/hip_runtime.h>

// PolynomialSketch: out[b,o] = (1/64)*exp(0.5*lv) * prod_k( sum_i x[b,i]*exp(-lls)*W[k,i,o] )
// B=16384, D_IN=1024, D_FEAT=4096, DEGREE=3

#define BATCH 16384
#define DIN   1024
#define DFEAT 4096

typedef short short8 __attribute__((ext_vector_type(8)));
typedef float f32x4  __attribute__((ext_vector_type(4)));
typedef unsigned short ushort8v __attribute__((ext_vector_type(8)));

__device__ __forceinline__ unsigned short f2bf(float f) {
  unsigned int u = __float_as_uint(f);
  u += 0x7FFFu + ((u >> 16) & 1u);   // round-to-nearest-even
  return (unsigned short)(u >> 16);
}

// ---- prelude 1: xs fragment-major = bf16(x * exp(-log_ls)) ----
// OUTPUT-INDEXED (round-8): thread i writes chunk i -> stores perfectly
// coalesced (R7 version scattered 16B stores at 25% efficiency). Reads become
// 16-row x 512B blocks, full-line use.
// Layout: chunk[(rb*32 + kc)*64 + l] (16B each); fragment (rb=row/16,kc=k/32):
// lane l holds row rb*16+(l&15), k = kc*32+(l>>4)*8.
__global__ void cast_x_kernel(const float4* __restrict__ x,
                              const float* __restrict__ log_ls,
                              ushort8v* __restrict__ xs) {
  float inv = expf(-log_ls[0]);
  int i  = blockIdx.x * 256 + threadIdx.x;   // output chunk id
  int l  = i & 63;
  int kc = (i >> 6) & 31;
  int rb = i >> 11;
  int r  = rb * 16 + (l & 15);
  int k8 = kc * 4 + (l >> 4);
  int src = (r * 128 + k8) * 2;
  float4 v0 = x[src];
  float4 v1 = x[src + 1];
  ushort8v o;
  o[0] = f2bf(v0.x * inv); o[1] = f2bf(v0.y * inv);
  o[2] = f2bf(v0.z * inv); o[3] = f2bf(v0.w * inv);
  o[4] = f2bf(v1.x * inv); o[5] = f2bf(v1.y * inv);
  o[6] = f2bf(v1.z * inv); o[7] = f2bf(v1.w * inv);
  xs[i] = o;
}

// ---- prelude 2: Wt[d, o, i] = bf16(W[d, i, o]) ----
__global__ void transpose_w_kernel(const float* __restrict__ W,
                                   unsigned short* __restrict__ Wt) {
  __shared__ float tile[32][65];
  int d  = blockIdx.z;
  int i0 = blockIdx.y * 32;   // d_in
  int o0 = blockIdx.x * 64;   // d_feat
  int tid = threadIdx.x;      // 0..255
  const float* src = W + (size_t)d * DIN * DFEAT + (size_t)i0 * DFEAT + o0;
  #pragma unroll
  for (int j = 0; j < 2; ++j) {
    int idx = j * 256 + tid;       // 0..511
    int r = idx >> 4;              // i row 0..31
    int c = (idx & 15) * 4;        // o col
    float4 v = *(const float4*)(src + (size_t)r * DFEAT + c);
    tile[r][c + 0] = v.x; tile[r][c + 1] = v.y;
    tile[r][c + 2] = v.z; tile[r][c + 3] = v.w;
  }
  __syncthreads();
  unsigned short* dst = Wt + (size_t)d * DFEAT * DIN + (size_t)o0 * DIN + i0;
  #pragma unroll
  for (int j = 0; j < 2; ++j) {
    int idx = j * 256 + tid;
    int r = idx >> 3;              // o row 0..63
    int c = (idx & 7) * 4;         // i col
    ushort4 u;
    u.x = f2bf(tile[c + 0][r]);
    u.y = f2bf(tile[c + 1][r]);
    u.z = f2bf(tile[c + 2][r]);
    u.w = f2bf(tile[c + 3][r]);
    *(ushort4*)(dst + (size_t)r * DIN + c) = u;
  }
}

// ---- main fused kernel ----
// BM=128, BN=64, BK=64. 256 threads = 4 waves in 2x2; wave tile 64x32 per degree.
// A direct-to-register from fragment-major xs; LDS holds only B (dbuf, 48 KiB,
// 2+ blocks/CU).
//
// ROUND-8: SINGLE BARRIER PER K-TILE + strength-reduced addressing.
// R7 counters: MfmaUtil 49.3 + VALUBusy 24.6 = 74% issue budget; ~26% stall
// across 3 barrier entries/tile; VALU dominated by re-computed addresses.
// New loop: per tile t: ENTRY(vmcnt(0)+barrier) -> 12 ds_read (all 3 B mats,
// precomputed addr + imm offset) -> stage tile t+1 (6 gload_lds + 8 A loads,
// fire-and-forget) -> 48 MFMA. Loads for tile t were issued a FULL tile
// (~1200cy) before ENTRY(t) waits on them -> latency covered; vmcnt(0) also
// makes the ledger immune to any compiler scratch traffic.
// Dbuf safety with ONE barrier: a wave's ds_reads of buf CB complete before
// its own MFMAs (reg data-dep), which precede its barrier arrival; staging
// into CB is only issued after that barrier -> no read/write race.
// B LDS: rows of 8 16B-chunks, chunk-XOR-swizzled phys p = c ^ (row&7),
// swizzle applied on the GLOBAL source address (linear gload_lds dest).
__global__ __launch_bounds__(256, 2) void sketch_gemm_kernel(
    const unsigned short* __restrict__ xs,   // fragment-major bf16 bits
    const unsigned short* __restrict__ Wt,   // [3][4096][1024] bf16 bits
    const float* __restrict__ log_var,
    float* __restrict__ out) {               // [16384][4096] fp32
  __shared__ unsigned short Bs[6 * 64 * 64];       // [buf][mat][4096], 48 KB

  const int tid  = threadIdx.x;
  const int lane = tid & 63;
  const int w    = tid >> 6;      // 0..3
  const int wm   = w >> 1;        // wave row (0..1)
  const int wn   = w & 1;         // wave col (0..1)
  const int row  = lane & 15;
  const int quad = lane >> 4;

  // XCD-aware mapping: bid % 8 -> XCD; 8 bn blocks per XCD slice (3 MB of B
  // fits 4 MB per-XCD L2); 8 consecutive blocks share one bm. 8192 % 8 == 0.
  int bid = blockIdx.x;
  int xcd = bid & 7;
  int t0  = bid >> 3;                // 0..1023 per XCD
  int bn  = (xcd << 3) + (t0 & 7);   // 0..63
  int bm  = t0 >> 3;                 // 0..127

  f32x4 acc[3][4][2];
  #pragma unroll
  for (int d = 0; d < 3; ++d)
    #pragma unroll
    for (int mi = 0; mi < 4; ++mi)
      #pragma unroll
      for (int ni = 0; ni < 2; ++ni)
        acc[d][mi][ni] = (f32x4){0.f, 0.f, 0.f, 0.f};

  const unsigned short* wsrc = Wt + (size_t)(bn * 64) * DIN;
  const int rbw = bm * 8 + wm * 4;   // wave's A row-block base

  // ---- precomputed (loop-invariant) addressing ----
  const int laneoff = lane * 8;      // A per-lane offset (ushort units)
  int soff[2];                       // STAGE_B per-lane source offset (ushorts)
  #pragma unroll
  for (int j = 0; j < 2; ++j) {
    int gc = ((w * 2 + j) << 6) + lane;     // chunk id 0..511
    int nn = gc >> 3;
    int cc = (gc & 7) ^ (nn & 7);
    soff[j] = nn * DIN + cc * 8;
  }
  int ba[2][2];                      // READ_B per-lane LDS byte offset
  #pragma unroll
  for (int ni = 0; ni < 2; ++ni)
    #pragma unroll
    for (int kh = 0; kh < 2; ++kh) {
      int nn = wn * 32 + ni * 16 + row;
      int pp = ((kh << 2) + quad) ^ (nn & 7);
      ba[ni][kh] = (nn * 64 + pp * 8) * 2;
    }

// stage all 3 B mats of K-window K0 into buffer NBUF (6 gload_lds/wave)
#define STAGE_B3(NBUF, K0)                                                     \
  _Pragma("unroll")                                                            \
  for (int mat = 0; mat < 3; ++mat)                                            \
    _Pragma("unroll")                                                          \
    for (int j = 0; j < 2; ++j)                                                \
      __builtin_amdgcn_global_load_lds(                                        \
          (const __attribute__((address_space(1))) void*)(                     \
              wsrc + (size_t)mat * (DFEAT * DIN) + (K0) + soff[j]),            \
          (__attribute__((address_space(3))) void*)(                           \
              &Bs[((NBUF) * 3 + mat) * 4096 + ((w * 2 + j) << 9)]),            \
          16, 0, 0);

// A fragments for tile T, direct from fragment-major xs (8 coalesced 16B loads)
#define LOAD_A(DST, T)                                                         \
  _Pragma("unroll")                                                            \
  for (int mi = 0; mi < 4; ++mi) {                                             \
    const unsigned short* pmi =                                                \
        xs + (size_t)((rbw + mi) * 32 + (T) * 2) * 512;                        \
    DST[mi][0] = *(const short8*)(pmi + laneoff);                              \
    DST[mi][1] = *(const short8*)(pmi + 512 + laneoff);                        \
  }

// read all 3 mats' B fragments from buffer CBUF (12 ds_read_b128, imm-folded)
#define READ_B_ALL(CBUF, DST)                                                  \
  _Pragma("unroll")                                                            \
  for (int mat = 0; mat < 3; ++mat)                                            \
    _Pragma("unroll")                                                          \
    for (int ni = 0; ni < 2; ++ni)                                             \
      _Pragma("unroll")                                                        \
      for (int kh = 0; kh < 2; ++kh)                                           \
        DST[mat][ni][kh] = *(const short8*)((const char*)Bs +                  \
            (((CBUF) * 3 + mat) * 8192) + ba[ni][kh]);

#define MFMA_ALL(AARR, BARR)                                                   \
  __builtin_amdgcn_s_setprio(1);                                               \
  _Pragma("unroll")                                                            \
  for (int mat = 0; mat < 3; ++mat)                                            \
    _Pragma("unroll")                                                          \
    for (int mi = 0; mi < 4; ++mi)                                             \
      _Pragma("unroll")                                                        \
      for (int ni = 0; ni < 2; ++ni)                                           \
        _Pragma("unroll")                                                      \
        for (int kh = 0; kh < 2; ++kh)                                         \
          acc[mat][mi][ni] = __builtin_amdgcn_mfma_f32_16x16x32_bf16(          \
              AARR[mi][kh], BARR[mat][ni][kh], acc[mat][mi][ni], 0, 0, 0);     \
  __builtin_amdgcn_s_setprio(0);

#define ENTRY0()                                                               \
  asm volatile("s_waitcnt vmcnt(0)" ::: "memory");                             \
  __builtin_amdgcn_s_barrier();                                                \
  __builtin_amdgcn_sched_barrier(0);

// one K-tile: single barrier; reads+prefetch then 48 MFMA.
#define TILE(T, AC, AA, CB, NB, PREFETCH)                                      \
  {                                                                            \
    ENTRY0();                                                                  \
    READ_B_ALL(CB, b);                                                         \
    if (PREFETCH) {                                                            \
      STAGE_B3(NB, ((T) + 1) * 64);                                            \
      LOAD_A(AA, (T) + 1);                                                     \
    }                                                                          \
    __builtin_amdgcn_sched_barrier(0);                                         \
    MFMA_ALL(AC, b);                                                           \
  }

  short8 a0[4][2], a1[4][2];
  short8 b[3][2][2];

  // prologue: stage tile 0 (B -> buf0, A -> a0); drained by TILE(0)'s ENTRY.
  STAGE_B3(0, 0);
  LOAD_A(a0, 0);

  #pragma unroll 1
  for (int i = 0; i < 7; ++i) {
    const int t = i * 2;
    TILE(t,     a0, a1, 0, 1, true);
    TILE(t + 1, a1, a0, 1, 0, true);
  }
  TILE(14, a0, a1, 0, 1, true);
  TILE(15, a1, a0, 1, 0, false);

  // epilogue: out = acc0*acc1*acc2 * (1/64)*exp(0.5*lv)
  float sc = 0.015625f * expf(0.5f * log_var[0]);
  #pragma unroll
  for (int mi = 0; mi < 4; ++mi) {
    #pragma unroll
    for (int ni = 0; ni < 2; ++ni) {
      int colg = bn * 64 + wn * 32 + ni * 16 + row;
      int rowg = bm * 128 + wm * 64 + mi * 16 + quad * 4;
      #pragma unroll
      for (int t2 = 0; t2 < 4; ++t2) {
        float v = acc[0][mi][ni][t2] * acc[1][mi][ni][t2] * acc[2][mi][ni][t2] * sc;
        out[(size_t)(rowg + t2) * DFEAT + colg] = v;
      }
    }
  }
#undef STAGE_B3
#undef LOAD_A
#undef READ_B_ALL
#undef MFMA_ALL
#undef ENTRY0
#undef TILE
}

extern "C" void kernel_launch(void* const* d_in, const int* in_sizes, int n_in,
                              void* d_out, int out_size, void* d_ws, size_t ws_size,
                              hipStream_t stream) {
  const float* x   = (const float*)d_in[0];
  const float* W   = (const float*)d_in[1];
  const float* lls = (const float*)d_in[2];
  const float* lv  = (const float*)d_in[3];
  float* out = (float*)d_out;

  unsigned short* xs = (unsigned short*)d_ws;                       // 32 MiB
  unsigned short* Wt = xs + (size_t)BATCH * DIN;                    // 24 MiB

  cast_x_kernel<<<BATCH * DIN / 8 / 256, 256, 0, stream>>>(
      (const float4*)x, lls, (ushort8v*)xs);

  transpose_w_kernel<<<dim3(DFEAT / 64, DIN / 32, 3), dim3(256), 0, stream>>>(W, Wt);

  sketch_gemm_kernel<<<(BATCH / 128) * (DFEAT / 64), 256, 0, stream>>>(xs, Wt, lv, out);
}